// Round 6
// baseline (483.854 us; speedup 1.0000x reference)
//
#include <hip/hip_runtime.h>
#include <math.h>

// CBTree contraction, B=4, L=9, d=256.
// g-combine before GEMM (linearity):
//   gL[p]=sum_b lc[b]*h[4p+b], gR[p]=sum_b rc[b]*h[4p+b]
//   h_new[p] = tanh([gL|gR] @ [Wl|Wr].T + vec[p])  (M=n_par, K=512, N=256)
//
// Round 10: tail restructure. Round 9 profile: cbt_rest=77us @ 0.3% MfmaUtil
// -> five 32-block kbars at ~13us each (acquire-load-per-spin + 32 spinners).
// Fix: exploit LOCAL tree dependencies. cbt_tail (8 blocks): block b computes
// L5 tiles 4b..4b+3 then L4 tile b (block-local, __syncthreads only). ONE
// light device barrier (relaxed spin, non-zero blocks exit w/o spinning).
// Then block 0 alone: L3 (2 tiles) -> L2 (M-guarded MFMA tile) -> L1 -> L0
// (exact fp32 VALU). L2 gains bf16-W quant (split-A keeps g exact):
// absmax est 0.0088 -> ~0.0095 vs threshold 0.02.
// Launches: wconv, l7 (512 blk), l6 (128 blk), tail (8 blk).

typedef __bf16 bf16x8 __attribute__((ext_vector_type(8)));
typedef __bf16 bf16x4 __attribute__((ext_vector_type(4)));
typedef float f32x4 __attribute__((ext_vector_type(4)));

__device__ __forceinline__ float fast_tanh(float x) {
    float ax = fabsf(x);
    float t = __builtin_amdgcn_exp2f(ax * -2.885390082f);  // 2*log2(e)
    float r = (1.0f - t) * __builtin_amdgcn_rcpf(1.0f + t);
    return copysignf(r, x);
}

// ---------------------------------------------------------------------------
// W swizzle: Wfrag holds [Wl|Wr] (N=256 x K=512) in MFMA B-fragment order.
// Fragment (J,T): 64 lanes x 8 bf16; lane L holds B[k=T*32+(L>>4)*8+j][n=J*16+(L&15)]
//   = Wcat[n][k].  Flat: Wfrag[(((J*16)+T)*64 + L)*8 + j]
// ---------------------------------------------------------------------------
__global__ __launch_bounds__(256) void cbt_wconv(
    const float* __restrict__ Wl, const float* __restrict__ Wr,
    __bf16* __restrict__ Wfrag)
{
    const int t = blockIdx.x * 256 + threadIdx.x;   // 0..16383
    const int L = t & 63;
    const int TJ = t >> 6;
    const int T = TJ & 15;
    const int J = TJ >> 4;
    const int n = J * 16 + (L & 15);
    const int k = T * 32 + (L >> 4) * 8;
    const float* src = (k < 256) ? (Wl + (size_t)n * 256 + k)
                                 : (Wr + (size_t)n * 256 + (k - 256));
    const float4 f0 = *reinterpret_cast<const float4*>(src);
    const float4 f1 = *reinterpret_cast<const float4*>(src + 4);
    bf16x8 o;
    o[0] = (__bf16)f0.x; o[1] = (__bf16)f0.y; o[2] = (__bf16)f0.z; o[3] = (__bf16)f0.w;
    o[4] = (__bf16)f1.x; o[5] = (__bf16)f1.y; o[6] = (__bf16)f1.z; o[7] = (__bf16)f1.w;
    *reinterpret_cast<bf16x8*>(Wfrag + (size_t)t * 8) = o;
}

// ---------------------------------------------------------------------------
// MFMA GEMM tile body. Tile 32 x 256 (full N), 256 threads (4 waves, 2x2).
// Single-pass child reads + split-A (hi+lo bf16) + double-buffered A LDS
// (one __syncthreads per K-iter). mLimit: number of valid output rows
// (M-guard for partial tiles; loads beyond read adjacent ws memory, results
// discarded — garbage/NaN in A row m affects only C row m, which is skipped).
// ---------------------------------------------------------------------------
template <typename CT, typename OT>
__device__ __forceinline__ void mfma_body(
    const CT* __restrict__ h,          // (4*M, 256) children
    const __bf16* __restrict__ Wfrag,  // swizzled weights
    const float* __restrict__ vec,     // (M, 256)
    OT* __restrict__ out,              // (M, 256)
    int mBase, __bf16* Alds, int mLimit)
{
    const int tid = threadIdx.x;
    const int lane = tid & 63;
    const int w = tid >> 6;
    const int wr = w >> 1, wc = w & 1;   // wave tile: rows wr*16, cols wc*128

    f32x4 acc[8] = {};

    // A staging: 8 threads per parent row, 4 cols each
    const int sm  = tid >> 3;            // parent row 0..31
    const int skq = (tid & 7) * 4;       // col offset 0..28
    const CT* hb = h + (size_t)(mBase + sm) * 1024 + skq;

    float c0[4], c1[4], c2[4], c3[4];
    auto load_h = [&](int k0) {
        if constexpr (sizeof(CT) == 4) {      // fp32 children
            const float4 a = *reinterpret_cast<const float4*>(hb + k0);
            const float4 b = *reinterpret_cast<const float4*>(hb + k0 + 256);
            const float4 c = *reinterpret_cast<const float4*>(hb + k0 + 512);
            const float4 d = *reinterpret_cast<const float4*>(hb + k0 + 768);
            c0[0] = a.x; c0[1] = a.y; c0[2] = a.z; c0[3] = a.w;
            c1[0] = b.x; c1[1] = b.y; c1[2] = b.z; c1[3] = b.w;
            c2[0] = c.x; c2[1] = c.y; c2[2] = c.z; c2[3] = c.w;
            c3[0] = d.x; c3[1] = d.y; c3[2] = d.z; c3[3] = d.w;
        } else {                              // bf16 children
            const bf16x4 a = *reinterpret_cast<const bf16x4*>(hb + k0);
            const bf16x4 b = *reinterpret_cast<const bf16x4*>(hb + k0 + 256);
            const bf16x4 c = *reinterpret_cast<const bf16x4*>(hb + k0 + 512);
            const bf16x4 d = *reinterpret_cast<const bf16x4*>(hb + k0 + 768);
#pragma unroll
            for (int j = 0; j < 4; ++j) {
                c0[j] = (float)a[j]; c1[j] = (float)b[j];
                c2[j] = (float)c[j]; c3[j] = (float)d[j];
            }
        }
    };

    auto store_A = [&](int buf) {
        constexpr float C23 = 2.0f / 3.0f, C13 = 1.0f / 3.0f;
        bf16x4 glh, gll, grh, grl;
#pragma unroll
        for (int j = 0; j < 4; ++j) {
            const float gl = c0[j] + C23 * c1[j] + C13 * c2[j];
            const float gr = C13 * c1[j] + C23 * c2[j] + c3[j];
            glh[j] = (__bf16)gl;
            gll[j] = (__bf16)(gl - (float)glh[j]);
            grh[j] = (__bf16)gr;
            grl[j] = (__bf16)(gr - (float)grh[j]);
        }
        const int o = buf * 5120 + sm * 40 + skq;
        *reinterpret_cast<bf16x4*>(&Alds[o])        = glh;
        *reinterpret_cast<bf16x4*>(&Alds[o + 1280]) = gll;
        *reinterpret_cast<bf16x4*>(&Alds[o + 2560]) = grh;
        *reinterpret_cast<bf16x4*>(&Alds[o + 3840]) = grl;
    };

    // B fragments: buf0 = current gL set, buf1 = current gR set; each slot
    // refilled with the next set right after its MFMAs (L1/L2-hot Wfrag).
    bf16x8 bfr[2][8];
    const __bf16* Wb = Wfrag + ((size_t)wc * 8192 + lane) * 8;  // J0=wc*8
    auto load_B = [&](int s, int buf) {
        const __bf16* p = Wb + (size_t)s * 512;
#pragma unroll
        for (int j = 0; j < 8; ++j)
            bfr[buf][j] = *reinterpret_cast<const bf16x8*>(p + (size_t)j * 8192);
    };

    // prologue: tile0 -> buf0; tile1 regs; first B sets
    load_h(0);
    load_B(0, 0);
    load_B(8, 1);
    store_A(0);
    load_h(32);
    __syncthreads();

    const int arow = (wr * 16 + (lane & 15)) * 40 + (lane >> 4) * 8;

    for (int T = 0; T < 8; ++T) {
        const int p = (T & 1) * 5120;
        const int q = ((T + 1) & 1);

        if (T < 7) store_A(q);             // tile T+1 -> other buffer
        if (T < 6) load_h((T + 2) * 32);   // tile T+2 -> regs

        const bf16x8 afLh = *reinterpret_cast<const bf16x8*>(&Alds[p + arow]);
        const bf16x8 afLl = *reinterpret_cast<const bf16x8*>(&Alds[p + arow + 1280]);
#pragma unroll
        for (int j = 0; j < 8; ++j)
            acc[j] = __builtin_amdgcn_mfma_f32_16x16x32_bf16(
                afLh, bfr[0][j], acc[j], 0, 0, 0);
#pragma unroll
        for (int j = 0; j < 8; ++j)
            acc[j] = __builtin_amdgcn_mfma_f32_16x16x32_bf16(
                afLl, bfr[0][j], acc[j], 0, 0, 0);

        if (T < 7) load_B(T + 1, 0);       // next gL B-set

        const bf16x8 afRh = *reinterpret_cast<const bf16x8*>(&Alds[p + arow + 2560]);
        const bf16x8 afRl = *reinterpret_cast<const bf16x8*>(&Alds[p + arow + 3840]);
#pragma unroll
        for (int j = 0; j < 8; ++j)
            acc[j] = __builtin_amdgcn_mfma_f32_16x16x32_bf16(
                afRh, bfr[1][j], acc[j], 0, 0, 0);
#pragma unroll
        for (int j = 0; j < 8; ++j)
            acc[j] = __builtin_amdgcn_mfma_f32_16x16x32_bf16(
                afRl, bfr[1][j], acc[j], 0, 0, 0);

        if (T < 7) load_B(T + 9, 1);       // next gR B-set

        if (T < 7) __syncthreads();        // tile T+1 now visible; reads of p done
    }

    // epilogue: C/D layout col=lane&15, row=(lane>>4)*4+reg
    const int q16 = lane >> 4, n16 = lane & 15;
    const int mrow = mBase + wr * 16 + q16 * 4;
#pragma unroll
    for (int j = 0; j < 8; ++j) {
        const int n = wc * 128 + j * 16 + n16;
#pragma unroll
        for (int r = 0; r < 4; ++r) {
            if (mrow + r < mLimit) {
                const size_t idx = (size_t)(mrow + r) * 256 + n;
                out[idx] = (OT)fast_tanh(acc[j][r] + vec[idx]);
            }
        }
    }
}

// ---------------------------------------------------------------------------
// K1: L7 (fp32 leaves -> bf16 out), 512 blocks.
// ---------------------------------------------------------------------------
__global__ __launch_bounds__(256, 2) void cbt_l7(
    const float* __restrict__ vectors, const __bf16* __restrict__ Wfrag,
    __bf16* __restrict__ buf7)
{
    __shared__ __align__(16) __bf16 Alds[8 * 32 * 40];
    mfma_body<float, __bf16>(vectors + (size_t)21845 * 256, Wfrag,
                             vectors + (size_t)5461 * 256, buf7,
                             (int)blockIdx.x * 32, Alds, 1 << 30);
}

// ---------------------------------------------------------------------------
// K2: L6 (bf16 children -> fp32 out), 128 blocks. Zeroes tail's barrier ctr.
// ---------------------------------------------------------------------------
__global__ __launch_bounds__(256, 2) void cbt_l6(
    const __bf16* __restrict__ h, const __bf16* __restrict__ Wfrag,
    const float* __restrict__ vec, float* __restrict__ out,
    unsigned* __restrict__ bar)
{
    if (blockIdx.x == 0 && threadIdx.x < 8) bar[threadIdx.x] = 0;
    __shared__ __align__(16) __bf16 Alds[8 * 32 * 40];
    mfma_body<__bf16, float>(h, Wfrag, vec, out, (int)blockIdx.x * 32, Alds,
                             1 << 30);
}

// ---------------------------------------------------------------------------
// Exact fp32 VALU level over full N=256 (single block): g-combine into LDS
// (G[m][k], stride 516), 16-lane-group dot products over K=512.
// ---------------------------------------------------------------------------
__device__ __forceinline__ void valu_full(
    const float* __restrict__ h, const float* __restrict__ Wl,
    const float* __restrict__ Wr, const float* __restrict__ vec,
    float* __restrict__ out, int M, float* G)
{
    const int tid = threadIdx.x;
    constexpr float C23 = 2.0f / 3.0f, C13 = 1.0f / 3.0f;
    constexpr int GS = 516;

    const int nelem = M * 512;
    for (int e = tid; e < nelem; e += 256) {
        const int m = e >> 9, k = e & 511;
        const float* hm = h + (size_t)m * 1024;
        float g;
        if (k < 256)
            g = hm[k] + C23 * hm[256 + k] + C13 * hm[512 + k];
        else {
            const int kk = k - 256;
            g = C13 * hm[256 + kk] + C23 * hm[512 + kk] + hm[768 + kk];
        }
        G[m * GS + k] = g;
    }
    __syncthreads();

    const int g16 = tid >> 4, l16 = tid & 15;
    const int nout = M * 256;
    for (int o = g16; o < nout; o += 16) {
        const int m = o >> 8;
        const int n = o & 255;
        const float* wlp = Wl + (size_t)n * 256;
        const float* wrp = Wr + (size_t)n * 256;
        float acc = 0.0f;
#pragma unroll
        for (int q = 0; q < 8; ++q) {
            const int k = l16 * 4 + q * 64;
            const float4 gv = *reinterpret_cast<const float4*>(&G[m * GS + k]);
            const float4 wv = (q < 4)
                ? *reinterpret_cast<const float4*>(wlp + k)
                : *reinterpret_cast<const float4*>(wrp + (k - 256));
            acc += gv.x * wv.x + gv.y * wv.y + gv.z * wv.z + gv.w * wv.w;
        }
#pragma unroll
        for (int off = 8; off >= 1; off >>= 1)
            acc += __shfl_xor(acc, off, 64);
        if (l16 == 0) {
            const size_t idx = (size_t)m * 256 + n;
            out[idx] = fast_tanh(acc + vec[idx]);
        }
    }
    __syncthreads();
}

// ---------------------------------------------------------------------------
// K3: L5..L0, 8 blocks, ONE device barrier.
// Block b: L5 tiles 4b..4b+3 (block-local), L4 tile b (needs exactly those
// L5 tiles). Barrier: everyone increments (release); blocks 1..7 exit;
// block 0 spins RELAXED until ==8, one acquire fence, then L3 (2 tiles),
// L2 (M-guarded MFMA, M=16), L1/L0 (exact fp32 VALU).
// ---------------------------------------------------------------------------
__global__ __launch_bounds__(256) void cbt_tail(
    const float* __restrict__ buf6, const __bf16* __restrict__ Wfrag,
    const float* __restrict__ Wl, const float* __restrict__ Wr,
    const float* __restrict__ vectors,
    float* __restrict__ buf5, float* __restrict__ buf4,
    float* __restrict__ buf3, float* __restrict__ buf2,
    float* __restrict__ buf1, float* __restrict__ outF,
    unsigned* __restrict__ bar)
{
    __shared__ __align__(16) __bf16 Alds[8 * 32 * 40];   // 20KB; aliased by G
    float* shG = (float*)Alds;                            // G needs <= 8.3KB (M=4)
    const int b = (int)blockIdx.x;
    const int tid = threadIdx.x;

    // phase A: 4x L5 tiles + 1x L4 tile, all block-local
#pragma unroll 1
    for (int t = 0; t < 4; ++t) {
        mfma_body<float, float>(buf6, Wfrag, vectors + (size_t)341 * 256, buf5,
                                (4 * b + t) * 32, Alds, 1 << 30);
        __syncthreads();
    }
    mfma_body<float, float>(buf5, Wfrag, vectors + (size_t)85 * 256, buf4,
                            b * 32, Alds, 1 << 30);
    __syncthreads();   // drain buf4 stores before signaling

    // single light barrier
    if (tid == 0) {
        __threadfence();   // release
        __hip_atomic_fetch_add(&bar[0], 1u, __ATOMIC_ACQ_REL,
                               __HIP_MEMORY_SCOPE_AGENT);
    }
    if (b != 0) return;
    if (tid == 0) {
        while (__hip_atomic_load(&bar[0], __ATOMIC_RELAXED,
                                 __HIP_MEMORY_SCOPE_AGENT) < 8u)
            __builtin_amdgcn_s_sleep(1);
        __threadfence();   // acquire
    }
    __syncthreads();

    // block 0: L3 (M=64, 2 full tiles)
    mfma_body<float, float>(buf4, Wfrag, vectors + (size_t)21 * 256, buf3,
                            0, Alds, 64);
    __syncthreads();
    mfma_body<float, float>(buf4, Wfrag, vectors + (size_t)21 * 256, buf3,
                            32, Alds, 64);
    __syncthreads();
    // L2 (M=16, guarded tile; child reads past buf3 hit adjacent ws, discarded)
    mfma_body<float, float>(buf3, Wfrag, vectors + (size_t)5 * 256, buf2,
                            0, Alds, 16);
    __syncthreads();
    // L1, L0: exact fp32
    valu_full(buf2, Wl, Wr, vectors + (size_t)1 * 256, buf1, 4, shG);
    valu_full(buf1, Wl, Wr, vectors, outF, 1, shG);
}

// ---------------------------------------------------------------------------
extern "C" void kernel_launch(void* const* d_in, const int* in_sizes, int n_in,
                              void* d_out, int out_size, void* d_ws, size_t ws_size,
                              hipStream_t stream) {
    const float* vectors = (const float*)d_in[0];
    const float* Wl = (const float*)d_in[1];
    const float* Wr = (const float*)d_in[2];
    float* outF = (float*)d_out;

    // ws layout:
    //   buf7  bf16  16384x256 (8 MB)   L7 out
    //   buf6  f32    4096x256 (4 MB)   L6 out
    //   buf5  f32    1024x256 (1 MB)   L5 out
    //   buf4  f32     256x256 (256 KB) L4 out
    //   buf3  f32      64x256 (64 KB)  L3 out
    //   buf2  f32      16x256 (16 KB)  L2 out
    //   buf1  f32       4x256 (4 KB)   L1 out
    //   Wfrag bf16  16384x8   (256 KB)
    //   bar   u32   x8        (32 B)
    char* p = (char*)d_ws;
    __bf16* buf7 = (__bf16*)p;           p += (size_t)16384 * 256 * 2;
    float*  buf6 = (float*)p;            p += (size_t)4096 * 256 * 4;
    float*  buf5 = (float*)p;            p += (size_t)1024 * 256 * 4;
    float*  buf4 = (float*)p;            p += (size_t)256 * 256 * 4;
    float*  buf3 = (float*)p;            p += (size_t)64 * 256 * 4;
    float*  buf2 = (float*)p;            p += (size_t)16 * 256 * 4;
    float*  buf1 = (float*)p;            p += (size_t)4 * 256 * 4;
    __bf16* Wfrag = (__bf16*)p;          p += (size_t)16384 * 8 * 2;
    unsigned* bar = (unsigned*)p;

    // K0: weight swizzle
    hipLaunchKernelGGL(cbt_wconv, dim3(64), dim3(256), 0, stream, Wl, Wr, Wfrag);
    // K1: L7 (512 tile-blocks)
    hipLaunchKernelGGL(cbt_l7, dim3(512), dim3(256), 0, stream,
                       vectors, Wfrag, buf7);
    // K2: L6 (also zeroes tail barrier counter)
    hipLaunchKernelGGL(cbt_l6, dim3(128), dim3(256), 0, stream,
                       buf7, Wfrag, vectors + (size_t)1365 * 256, buf6, bar);
    // K3: L5..L0 (8 blocks, one internal barrier)
    hipLaunchKernelGGL(cbt_tail, dim3(8), dim3(256), 0, stream,
                       buf6, Wfrag, Wl, Wr, vectors,
                       buf5, buf4, buf3, buf2, buf1, outF, bar);
}

// Round 7
// 434.739 us; speedup vs baseline: 1.1130x; 1.1130x over previous
//
#include <hip/hip_runtime.h>
#include <math.h>

// CBTree contraction, B=4, L=9, d=256.
// g-combine before GEMM (linearity):
//   gL[p]=sum_b lc[b]*h[4p+b], gR[p]=sum_b rc[b]*h[4p+b]
//   h_new[p] = tanh([gL|gR] @ [Wl|Wr].T + vec[p])  (M=n_par, K=512, N=256)
//
// Round 11: NO cross-block spins anywhere. Round 10's relaxed agent-scope
// spin never invalidated the local cache -> ~300us stall. Revised cost
// model from rounds 6/9/10: two harness poison-fills ~104us are inside the
// timed region (immovable); launch gaps are only ~3us (graph capture).
// Structure: 5 plain launches, block-local tree deps for the tail:
//   wconv (64 blk) | l7 (512 blk) | l6 (128 blk)
//   l5l4 (8 blk): block b = L5 tiles 4b..4b+3 then L4 tile b (block-local)
//   tail1 (1 blk): L3 (2 MFMA tiles) -> L2 (M-guarded MFMA) -> L1/L0
//                  (exact fp32 VALU)
// Numerics identical to round 10 (absmax 0.01367): split-A hi/lo bf16-W
// MFMA for L7..L2, fp32 intermediates, exact fp32 L1/L0.

typedef __bf16 bf16x8 __attribute__((ext_vector_type(8)));
typedef __bf16 bf16x4 __attribute__((ext_vector_type(4)));
typedef float f32x4 __attribute__((ext_vector_type(4)));

__device__ __forceinline__ float fast_tanh(float x) {
    float ax = fabsf(x);
    float t = __builtin_amdgcn_exp2f(ax * -2.885390082f);  // 2*log2(e)
    float r = (1.0f - t) * __builtin_amdgcn_rcpf(1.0f + t);
    return copysignf(r, x);
}

// ---------------------------------------------------------------------------
// W swizzle: Wfrag holds [Wl|Wr] (N=256 x K=512) in MFMA B-fragment order.
// Fragment (J,T): 64 lanes x 8 bf16; lane L holds B[k=T*32+(L>>4)*8+j][n=J*16+(L&15)]
//   = Wcat[n][k].  Flat: Wfrag[(((J*16)+T)*64 + L)*8 + j]
// ---------------------------------------------------------------------------
__global__ __launch_bounds__(256) void cbt_wconv(
    const float* __restrict__ Wl, const float* __restrict__ Wr,
    __bf16* __restrict__ Wfrag)
{
    const int t = blockIdx.x * 256 + threadIdx.x;   // 0..16383
    const int L = t & 63;
    const int TJ = t >> 6;
    const int T = TJ & 15;
    const int J = TJ >> 4;
    const int n = J * 16 + (L & 15);
    const int k = T * 32 + (L >> 4) * 8;
    const float* src = (k < 256) ? (Wl + (size_t)n * 256 + k)
                                 : (Wr + (size_t)n * 256 + (k - 256));
    const float4 f0 = *reinterpret_cast<const float4*>(src);
    const float4 f1 = *reinterpret_cast<const float4*>(src + 4);
    bf16x8 o;
    o[0] = (__bf16)f0.x; o[1] = (__bf16)f0.y; o[2] = (__bf16)f0.z; o[3] = (__bf16)f0.w;
    o[4] = (__bf16)f1.x; o[5] = (__bf16)f1.y; o[6] = (__bf16)f1.z; o[7] = (__bf16)f1.w;
    *reinterpret_cast<bf16x8*>(Wfrag + (size_t)t * 8) = o;
}

// ---------------------------------------------------------------------------
// MFMA GEMM tile body. Tile 32 x 256 (full N), 256 threads (4 waves, 2x2).
// Single-pass child reads + split-A (hi+lo bf16) + double-buffered A LDS
// (one __syncthreads per K-iter). mLimit: valid output rows (M-guard for
// partial tiles; A rows beyond read adjacent ws memory -> garbage confined
// to C rows that are skipped).
// ---------------------------------------------------------------------------
template <typename CT, typename OT>
__device__ __forceinline__ void mfma_body(
    const CT* __restrict__ h,          // (4*M, 256) children
    const __bf16* __restrict__ Wfrag,  // swizzled weights
    const float* __restrict__ vec,     // (M, 256)
    OT* __restrict__ out,              // (M, 256)
    int mBase, __bf16* Alds, int mLimit)
{
    const int tid = threadIdx.x;
    const int lane = tid & 63;
    const int w = tid >> 6;
    const int wr = w >> 1, wc = w & 1;   // wave tile: rows wr*16, cols wc*128

    f32x4 acc[8] = {};

    // A staging: 8 threads per parent row, 4 cols each
    const int sm  = tid >> 3;            // parent row 0..31
    const int skq = (tid & 7) * 4;       // col offset 0..28
    const CT* hb = h + (size_t)(mBase + sm) * 1024 + skq;

    float c0[4], c1[4], c2[4], c3[4];
    auto load_h = [&](int k0) {
        if constexpr (sizeof(CT) == 4) {      // fp32 children
            const float4 a = *reinterpret_cast<const float4*>(hb + k0);
            const float4 b = *reinterpret_cast<const float4*>(hb + k0 + 256);
            const float4 c = *reinterpret_cast<const float4*>(hb + k0 + 512);
            const float4 d = *reinterpret_cast<const float4*>(hb + k0 + 768);
            c0[0] = a.x; c0[1] = a.y; c0[2] = a.z; c0[3] = a.w;
            c1[0] = b.x; c1[1] = b.y; c1[2] = b.z; c1[3] = b.w;
            c2[0] = c.x; c2[1] = c.y; c2[2] = c.z; c2[3] = c.w;
            c3[0] = d.x; c3[1] = d.y; c3[2] = d.z; c3[3] = d.w;
        } else {                              // bf16 children
            const bf16x4 a = *reinterpret_cast<const bf16x4*>(hb + k0);
            const bf16x4 b = *reinterpret_cast<const bf16x4*>(hb + k0 + 256);
            const bf16x4 c = *reinterpret_cast<const bf16x4*>(hb + k0 + 512);
            const bf16x4 d = *reinterpret_cast<const bf16x4*>(hb + k0 + 768);
#pragma unroll
            for (int j = 0; j < 4; ++j) {
                c0[j] = (float)a[j]; c1[j] = (float)b[j];
                c2[j] = (float)c[j]; c3[j] = (float)d[j];
            }
        }
    };

    auto store_A = [&](int buf) {
        constexpr float C23 = 2.0f / 3.0f, C13 = 1.0f / 3.0f;
        bf16x4 glh, gll, grh, grl;
#pragma unroll
        for (int j = 0; j < 4; ++j) {
            const float gl = c0[j] + C23 * c1[j] + C13 * c2[j];
            const float gr = C13 * c1[j] + C23 * c2[j] + c3[j];
            glh[j] = (__bf16)gl;
            gll[j] = (__bf16)(gl - (float)glh[j]);
            grh[j] = (__bf16)gr;
            grl[j] = (__bf16)(gr - (float)grh[j]);
        }
        const int o = buf * 5120 + sm * 40 + skq;
        *reinterpret_cast<bf16x4*>(&Alds[o])        = glh;
        *reinterpret_cast<bf16x4*>(&Alds[o + 1280]) = gll;
        *reinterpret_cast<bf16x4*>(&Alds[o + 2560]) = grh;
        *reinterpret_cast<bf16x4*>(&Alds[o + 3840]) = grl;
    };

    // B fragments: buf0 = current gL set, buf1 = current gR set; each slot
    // refilled with the next set right after its MFMAs (L1/L2-hot Wfrag).
    bf16x8 bfr[2][8];
    const __bf16* Wb = Wfrag + ((size_t)wc * 8192 + lane) * 8;  // J0=wc*8
    auto load_B = [&](int s, int buf) {
        const __bf16* p = Wb + (size_t)s * 512;
#pragma unroll
        for (int j = 0; j < 8; ++j)
            bfr[buf][j] = *reinterpret_cast<const bf16x8*>(p + (size_t)j * 8192);
    };

    // prologue: tile0 -> buf0; tile1 regs; first B sets
    load_h(0);
    load_B(0, 0);
    load_B(8, 1);
    store_A(0);
    load_h(32);
    __syncthreads();

    const int arow = (wr * 16 + (lane & 15)) * 40 + (lane >> 4) * 8;

    for (int T = 0; T < 8; ++T) {
        const int p = (T & 1) * 5120;
        const int q = ((T + 1) & 1);

        if (T < 7) store_A(q);             // tile T+1 -> other buffer
        if (T < 6) load_h((T + 2) * 32);   // tile T+2 -> regs

        const bf16x8 afLh = *reinterpret_cast<const bf16x8*>(&Alds[p + arow]);
        const bf16x8 afLl = *reinterpret_cast<const bf16x8*>(&Alds[p + arow + 1280]);
#pragma unroll
        for (int j = 0; j < 8; ++j)
            acc[j] = __builtin_amdgcn_mfma_f32_16x16x32_bf16(
                afLh, bfr[0][j], acc[j], 0, 0, 0);
#pragma unroll
        for (int j = 0; j < 8; ++j)
            acc[j] = __builtin_amdgcn_mfma_f32_16x16x32_bf16(
                afLl, bfr[0][j], acc[j], 0, 0, 0);

        if (T < 7) load_B(T + 1, 0);       // next gL B-set

        const bf16x8 afRh = *reinterpret_cast<const bf16x8*>(&Alds[p + arow + 2560]);
        const bf16x8 afRl = *reinterpret_cast<const bf16x8*>(&Alds[p + arow + 3840]);
#pragma unroll
        for (int j = 0; j < 8; ++j)
            acc[j] = __builtin_amdgcn_mfma_f32_16x16x32_bf16(
                afRh, bfr[1][j], acc[j], 0, 0, 0);
#pragma unroll
        for (int j = 0; j < 8; ++j)
            acc[j] = __builtin_amdgcn_mfma_f32_16x16x32_bf16(
                afRl, bfr[1][j], acc[j], 0, 0, 0);

        if (T < 7) load_B(T + 9, 1);       // next gR B-set

        if (T < 7) __syncthreads();        // tile T+1 now visible; reads of p done
    }

    // epilogue: C/D layout col=lane&15, row=(lane>>4)*4+reg
    const int q16 = lane >> 4, n16 = lane & 15;
    const int mrow = mBase + wr * 16 + q16 * 4;
#pragma unroll
    for (int j = 0; j < 8; ++j) {
        const int n = wc * 128 + j * 16 + n16;
#pragma unroll
        for (int r = 0; r < 4; ++r) {
            if (mrow + r < mLimit) {
                const size_t idx = (size_t)(mrow + r) * 256 + n;
                out[idx] = (OT)fast_tanh(acc[j][r] + vec[idx]);
            }
        }
    }
}

// ---------------------------------------------------------------------------
// K1: L7 (fp32 leaves -> bf16 out), 512 blocks.
// ---------------------------------------------------------------------------
__global__ __launch_bounds__(256, 2) void cbt_l7(
    const float* __restrict__ vectors, const __bf16* __restrict__ Wfrag,
    __bf16* __restrict__ buf7)
{
    __shared__ __align__(16) __bf16 Alds[8 * 32 * 40];
    mfma_body<float, __bf16>(vectors + (size_t)21845 * 256, Wfrag,
                             vectors + (size_t)5461 * 256, buf7,
                             (int)blockIdx.x * 32, Alds, 1 << 30);
}

// ---------------------------------------------------------------------------
// K2: L6 (bf16 children -> fp32 out), 128 blocks.
// ---------------------------------------------------------------------------
__global__ __launch_bounds__(256, 2) void cbt_l6(
    const __bf16* __restrict__ h, const __bf16* __restrict__ Wfrag,
    const float* __restrict__ vec, float* __restrict__ out)
{
    __shared__ __align__(16) __bf16 Alds[8 * 32 * 40];
    mfma_body<__bf16, float>(h, Wfrag, vec, out, (int)blockIdx.x * 32, Alds,
                             1 << 30);
}

// ---------------------------------------------------------------------------
// K3: L5 + L4, 8 blocks, purely block-local dependencies (__syncthreads
// only). Block b: L5 tiles 4b..4b+3 (buf6 -> buf5 rows 128b..128b+127),
// then L4 tile b (reads exactly those buf5 rows -> buf4 rows 32b..32b+31).
// Same-block global RW coherence: stores drained by __syncthreads (vmcnt 0),
// L1 lines invalidated on write (proven on-silicon by round 10 phase A).
// ---------------------------------------------------------------------------
__global__ __launch_bounds__(256) void cbt_l5l4(
    const float* __restrict__ buf6, const __bf16* __restrict__ Wfrag,
    const float* __restrict__ vectors,
    float* __restrict__ buf5, float* __restrict__ buf4)
{
    __shared__ __align__(16) __bf16 Alds[8 * 32 * 40];
    const int b = (int)blockIdx.x;
#pragma unroll 1
    for (int t = 0; t < 4; ++t) {
        mfma_body<float, float>(buf6, Wfrag, vectors + (size_t)341 * 256, buf5,
                                (4 * b + t) * 32, Alds, 1 << 30);
        __syncthreads();
    }
    mfma_body<float, float>(buf5, Wfrag, vectors + (size_t)85 * 256, buf4,
                            b * 32, Alds, 1 << 30);
}

// ---------------------------------------------------------------------------
// Exact fp32 VALU level over full N=256 (single block): g-combine into LDS
// (G[m][k], stride 516), 16-lane-group dot products over K=512. M <= 4.
// ---------------------------------------------------------------------------
__device__ __forceinline__ void valu_full(
    const float* __restrict__ h, const float* __restrict__ Wl,
    const float* __restrict__ Wr, const float* __restrict__ vec,
    float* __restrict__ out, int M, float* G)
{
    const int tid = threadIdx.x;
    constexpr float C23 = 2.0f / 3.0f, C13 = 1.0f / 3.0f;
    constexpr int GS = 516;

    const int nelem = M * 512;
    for (int e = tid; e < nelem; e += 256) {
        const int m = e >> 9, k = e & 511;
        const float* hm = h + (size_t)m * 1024;
        float g;
        if (k < 256)
            g = hm[k] + C23 * hm[256 + k] + C13 * hm[512 + k];
        else {
            const int kk = k - 256;
            g = C13 * hm[256 + kk] + C23 * hm[512 + kk] + hm[768 + kk];
        }
        G[m * GS + k] = g;
    }
    __syncthreads();

    const int g16 = tid >> 4, l16 = tid & 15;
    const int nout = M * 256;
    for (int o = g16; o < nout; o += 16) {
        const int m = o >> 8;
        const int n = o & 255;
        const float* wlp = Wl + (size_t)n * 256;
        const float* wrp = Wr + (size_t)n * 256;
        float acc = 0.0f;
#pragma unroll
        for (int q = 0; q < 8; ++q) {
            const int k = l16 * 4 + q * 64;
            const float4 gv = *reinterpret_cast<const float4*>(&G[m * GS + k]);
            const float4 wv = (q < 4)
                ? *reinterpret_cast<const float4*>(wlp + k)
                : *reinterpret_cast<const float4*>(wrp + (k - 256));
            acc += gv.x * wv.x + gv.y * wv.y + gv.z * wv.z + gv.w * wv.w;
        }
#pragma unroll
        for (int off = 8; off >= 1; off >>= 1)
            acc += __shfl_xor(acc, off, 64);
        if (l16 == 0) {
            const size_t idx = (size_t)m * 256 + n;
            out[idx] = fast_tanh(acc + vec[idx]);
        }
    }
    __syncthreads();
}

// ---------------------------------------------------------------------------
// K4: L3..L0 in ONE block (cross-block dep on buf4 crosses the kernel
// boundary). L3: 2 full MFMA tiles. L2: M-guarded MFMA tile (M=16; A rows
// 16..31 read adjacent ws, discarded). L1/L0: exact fp32 VALU.
// ---------------------------------------------------------------------------
__global__ __launch_bounds__(256) void cbt_tail1(
    const float* __restrict__ buf4, const __bf16* __restrict__ Wfrag,
    const float* __restrict__ Wl, const float* __restrict__ Wr,
    const float* __restrict__ vectors,
    float* __restrict__ buf3, float* __restrict__ buf2,
    float* __restrict__ buf1, float* __restrict__ outF)
{
    __shared__ __align__(16) __bf16 Alds[8 * 32 * 40];   // 20 KB
    __shared__ __align__(16) float shG[4 * 516];         // 8.3 KB (M<=4 valu)

    // L3: M=64 (2 full tiles), buf4 -> buf3
    mfma_body<float, float>(buf4, Wfrag, vectors + (size_t)21 * 256, buf3,
                            0, Alds, 1 << 30);
    __syncthreads();
    mfma_body<float, float>(buf4, Wfrag, vectors + (size_t)21 * 256, buf3,
                            32, Alds, 1 << 30);
    __syncthreads();
    // L2: M=16 (guarded), buf3 -> buf2
    mfma_body<float, float>(buf3, Wfrag, vectors + (size_t)5 * 256, buf2,
                            0, Alds, 16);
    __syncthreads();
    // L1, L0: exact fp32
    valu_full(buf2, Wl, Wr, vectors + (size_t)1 * 256, buf1, 4, shG);
    valu_full(buf1, Wl, Wr, vectors, outF, 1, shG);
}

// ---------------------------------------------------------------------------
extern "C" void kernel_launch(void* const* d_in, const int* in_sizes, int n_in,
                              void* d_out, int out_size, void* d_ws, size_t ws_size,
                              hipStream_t stream) {
    const float* vectors = (const float*)d_in[0];
    const float* Wl = (const float*)d_in[1];
    const float* Wr = (const float*)d_in[2];
    float* outF = (float*)d_out;

    // ws layout:
    //   buf7  bf16  16384x256 (8 MB)   L7 out
    //   buf6  f32    4096x256 (4 MB)   L6 out
    //   buf5  f32    1024x256 (1 MB)   L5 out
    //   buf4  f32     256x256 (256 KB) L4 out
    //   buf3  f32      64x256 (64 KB)  L3 out
    //   buf2  f32      16x256 (16 KB)  L2 out
    //   buf1  f32       4x256 (4 KB)   L1 out
    //   Wfrag bf16  16384x8   (256 KB)
    char* p = (char*)d_ws;
    __bf16* buf7 = (__bf16*)p;           p += (size_t)16384 * 256 * 2;
    float*  buf6 = (float*)p;            p += (size_t)4096 * 256 * 4;
    float*  buf5 = (float*)p;            p += (size_t)1024 * 256 * 4;
    float*  buf4 = (float*)p;            p += (size_t)256 * 256 * 4;
    float*  buf3 = (float*)p;            p += (size_t)64 * 256 * 4;
    float*  buf2 = (float*)p;            p += (size_t)16 * 256 * 4;
    float*  buf1 = (float*)p;            p += (size_t)4 * 256 * 4;
    __bf16* Wfrag = (__bf16*)p;

    // K0: weight swizzle
    hipLaunchKernelGGL(cbt_wconv, dim3(64), dim3(256), 0, stream, Wl, Wr, Wfrag);
    // K1: L7 (512 tile-blocks)
    hipLaunchKernelGGL(cbt_l7, dim3(512), dim3(256), 0, stream,
                       vectors, Wfrag, buf7);
    // K2: L6
    hipLaunchKernelGGL(cbt_l6, dim3(128), dim3(256), 0, stream,
                       buf7, Wfrag, vectors + (size_t)1365 * 256, buf6);
    // K3: L5+L4 (8 blocks, block-local deps)
    hipLaunchKernelGGL(cbt_l5l4, dim3(8), dim3(256), 0, stream,
                       buf6, Wfrag, vectors, buf5, buf4);
    // K4: L3..L0 (1 block)
    hipLaunchKernelGGL(cbt_tail1, dim3(1), dim3(256), 0, stream,
                       buf4, Wfrag, Wl, Wr, vectors, buf3, buf2, buf1, outF);
}

// Round 8
// 406.635 us; speedup vs baseline: 1.1899x; 1.0691x over previous
//
#include <hip/hip_runtime.h>
#include <math.h>

// CBTree contraction, B=4, L=9, d=256.
// g-combine before GEMM (linearity):
//   gL[p]=sum_b lc[b]*h[4p+b], gR[p]=sum_b rc[b]*h[4p+b]
//   h_new[p] = tanh([gL|gR] @ [Wl|Wr].T + vec[p])  (M=n_par, K=512, N=256)
//
// Round 12: single-instance tail kernels. Round 11 profile: cbt_l5l4=173us
// @0.15% MfmaUtil with 5 inlined mfma_body copies (~100KB straight-line
// code, executed once -> every line a cold I-fetch on an idle CU) + VGPR=256
// with ~2.7MB spill stores (WRITE_SIZE 4.0MB vs 1.3MB real). cbt_tail1 ~110us
// same disease. Fix: ONE mfma_body instance per kernel, driven by a job loop
// (#pragma unroll 1, runtime ptrs in SGPRs via if-chains). Code ~5x smaller,
// I-cache hot after job 0, single-instance regalloc -> no spills.
// Numerics bit-identical to round 11 (absmax 0.01367).
// Launches: wconv (64) | l7 (512) | l6 (128) | l5l4 (8) | tail1 (1).

typedef __bf16 bf16x8 __attribute__((ext_vector_type(8)));
typedef __bf16 bf16x4 __attribute__((ext_vector_type(4)));
typedef float f32x4 __attribute__((ext_vector_type(4)));

__device__ __forceinline__ float fast_tanh(float x) {
    float ax = fabsf(x);
    float t = __builtin_amdgcn_exp2f(ax * -2.885390082f);  // 2*log2(e)
    float r = (1.0f - t) * __builtin_amdgcn_rcpf(1.0f + t);
    return copysignf(r, x);
}

// ---------------------------------------------------------------------------
// W swizzle: Wfrag holds [Wl|Wr] (N=256 x K=512) in MFMA B-fragment order.
// Fragment (J,T): 64 lanes x 8 bf16; lane L holds B[k=T*32+(L>>4)*8+j][n=J*16+(L&15)]
//   = Wcat[n][k].  Flat: Wfrag[(((J*16)+T)*64 + L)*8 + j]
// ---------------------------------------------------------------------------
__global__ __launch_bounds__(256) void cbt_wconv(
    const float* __restrict__ Wl, const float* __restrict__ Wr,
    __bf16* __restrict__ Wfrag)
{
    const int t = blockIdx.x * 256 + threadIdx.x;   // 0..16383
    const int L = t & 63;
    const int TJ = t >> 6;
    const int T = TJ & 15;
    const int J = TJ >> 4;
    const int n = J * 16 + (L & 15);
    const int k = T * 32 + (L >> 4) * 8;
    const float* src = (k < 256) ? (Wl + (size_t)n * 256 + k)
                                 : (Wr + (size_t)n * 256 + (k - 256));
    const float4 f0 = *reinterpret_cast<const float4*>(src);
    const float4 f1 = *reinterpret_cast<const float4*>(src + 4);
    bf16x8 o;
    o[0] = (__bf16)f0.x; o[1] = (__bf16)f0.y; o[2] = (__bf16)f0.z; o[3] = (__bf16)f0.w;
    o[4] = (__bf16)f1.x; o[5] = (__bf16)f1.y; o[6] = (__bf16)f1.z; o[7] = (__bf16)f1.w;
    *reinterpret_cast<bf16x8*>(Wfrag + (size_t)t * 8) = o;
}

// ---------------------------------------------------------------------------
// MFMA GEMM tile body. Tile 32 x 256 (full N), 256 threads (4 waves, 2x2).
// Single-pass child reads + split-A (hi+lo bf16) + double-buffered A LDS
// (one __syncthreads per K-iter). mLimit: valid output rows (M-guard for
// partial tiles; A rows beyond read adjacent ws memory -> garbage confined
// to C rows that are skipped).
// ---------------------------------------------------------------------------
template <typename CT, typename OT>
__device__ __forceinline__ void mfma_body(
    const CT* __restrict__ h,          // (4*M, 256) children
    const __bf16* __restrict__ Wfrag,  // swizzled weights
    const float* __restrict__ vec,     // (M, 256)
    OT* __restrict__ out,              // (M, 256)
    int mBase, __bf16* Alds, int mLimit)
{
    const int tid = threadIdx.x;
    const int lane = tid & 63;
    const int w = tid >> 6;
    const int wr = w >> 1, wc = w & 1;   // wave tile: rows wr*16, cols wc*128

    f32x4 acc[8] = {};

    // A staging: 8 threads per parent row, 4 cols each
    const int sm  = tid >> 3;            // parent row 0..31
    const int skq = (tid & 7) * 4;       // col offset 0..28
    const CT* hb = h + (size_t)(mBase + sm) * 1024 + skq;

    float c0[4], c1[4], c2[4], c3[4];
    auto load_h = [&](int k0) {
        if constexpr (sizeof(CT) == 4) {      // fp32 children
            const float4 a = *reinterpret_cast<const float4*>(hb + k0);
            const float4 b = *reinterpret_cast<const float4*>(hb + k0 + 256);
            const float4 c = *reinterpret_cast<const float4*>(hb + k0 + 512);
            const float4 d = *reinterpret_cast<const float4*>(hb + k0 + 768);
            c0[0] = a.x; c0[1] = a.y; c0[2] = a.z; c0[3] = a.w;
            c1[0] = b.x; c1[1] = b.y; c1[2] = b.z; c1[3] = b.w;
            c2[0] = c.x; c2[1] = c.y; c2[2] = c.z; c2[3] = c.w;
            c3[0] = d.x; c3[1] = d.y; c3[2] = d.z; c3[3] = d.w;
        } else {                              // bf16 children
            const bf16x4 a = *reinterpret_cast<const bf16x4*>(hb + k0);
            const bf16x4 b = *reinterpret_cast<const bf16x4*>(hb + k0 + 256);
            const bf16x4 c = *reinterpret_cast<const bf16x4*>(hb + k0 + 512);
            const bf16x4 d = *reinterpret_cast<const bf16x4*>(hb + k0 + 768);
#pragma unroll
            for (int j = 0; j < 4; ++j) {
                c0[j] = (float)a[j]; c1[j] = (float)b[j];
                c2[j] = (float)c[j]; c3[j] = (float)d[j];
            }
        }
    };

    auto store_A = [&](int buf) {
        constexpr float C23 = 2.0f / 3.0f, C13 = 1.0f / 3.0f;
        bf16x4 glh, gll, grh, grl;
#pragma unroll
        for (int j = 0; j < 4; ++j) {
            const float gl = c0[j] + C23 * c1[j] + C13 * c2[j];
            const float gr = C13 * c1[j] + C23 * c2[j] + c3[j];
            glh[j] = (__bf16)gl;
            gll[j] = (__bf16)(gl - (float)glh[j]);
            grh[j] = (__bf16)gr;
            grl[j] = (__bf16)(gr - (float)grh[j]);
        }
        const int o = buf * 5120 + sm * 40 + skq;
        *reinterpret_cast<bf16x4*>(&Alds[o])        = glh;
        *reinterpret_cast<bf16x4*>(&Alds[o + 1280]) = gll;
        *reinterpret_cast<bf16x4*>(&Alds[o + 2560]) = grh;
        *reinterpret_cast<bf16x4*>(&Alds[o + 3840]) = grl;
    };

    // B fragments: buf0 = current gL set, buf1 = current gR set; each slot
    // refilled with the next set right after its MFMAs (L1/L2-hot Wfrag).
    bf16x8 bfr[2][8];
    const __bf16* Wb = Wfrag + ((size_t)wc * 8192 + lane) * 8;  // J0=wc*8
    auto load_B = [&](int s, int buf) {
        const __bf16* p = Wb + (size_t)s * 512;
#pragma unroll
        for (int j = 0; j < 8; ++j)
            bfr[buf][j] = *reinterpret_cast<const bf16x8*>(p + (size_t)j * 8192);
    };

    // prologue: tile0 -> buf0; tile1 regs; first B sets
    load_h(0);
    load_B(0, 0);
    load_B(8, 1);
    store_A(0);
    load_h(32);
    __syncthreads();

    const int arow = (wr * 16 + (lane & 15)) * 40 + (lane >> 4) * 8;

    for (int T = 0; T < 8; ++T) {
        const int p = (T & 1) * 5120;
        const int q = ((T + 1) & 1);

        if (T < 7) store_A(q);             // tile T+1 -> other buffer
        if (T < 6) load_h((T + 2) * 32);   // tile T+2 -> regs

        const bf16x8 afLh = *reinterpret_cast<const bf16x8*>(&Alds[p + arow]);
        const bf16x8 afLl = *reinterpret_cast<const bf16x8*>(&Alds[p + arow + 1280]);
#pragma unroll
        for (int j = 0; j < 8; ++j)
            acc[j] = __builtin_amdgcn_mfma_f32_16x16x32_bf16(
                afLh, bfr[0][j], acc[j], 0, 0, 0);
#pragma unroll
        for (int j = 0; j < 8; ++j)
            acc[j] = __builtin_amdgcn_mfma_f32_16x16x32_bf16(
                afLl, bfr[0][j], acc[j], 0, 0, 0);

        if (T < 7) load_B(T + 1, 0);       // next gL B-set

        const bf16x8 afRh = *reinterpret_cast<const bf16x8*>(&Alds[p + arow + 2560]);
        const bf16x8 afRl = *reinterpret_cast<const bf16x8*>(&Alds[p + arow + 3840]);
#pragma unroll
        for (int j = 0; j < 8; ++j)
            acc[j] = __builtin_amdgcn_mfma_f32_16x16x32_bf16(
                afRh, bfr[1][j], acc[j], 0, 0, 0);
#pragma unroll
        for (int j = 0; j < 8; ++j)
            acc[j] = __builtin_amdgcn_mfma_f32_16x16x32_bf16(
                afRl, bfr[1][j], acc[j], 0, 0, 0);

        if (T < 7) load_B(T + 9, 1);       // next gR B-set

        if (T < 7) __syncthreads();        // tile T+1 now visible; reads of p done
    }

    // epilogue: C/D layout col=lane&15, row=(lane>>4)*4+reg
    const int q16 = lane >> 4, n16 = lane & 15;
    const int mrow = mBase + wr * 16 + q16 * 4;
#pragma unroll
    for (int j = 0; j < 8; ++j) {
        const int n = wc * 128 + j * 16 + n16;
#pragma unroll
        for (int r = 0; r < 4; ++r) {
            if (mrow + r < mLimit) {
                const size_t idx = (size_t)(mrow + r) * 256 + n;
                out[idx] = (OT)fast_tanh(acc[j][r] + vec[idx]);
            }
        }
    }
}

// ---------------------------------------------------------------------------
// K1: L7 (fp32 leaves -> bf16 out), 512 blocks. One mfma_body instance.
// ---------------------------------------------------------------------------
__global__ __launch_bounds__(256, 2) void cbt_l7(
    const float* __restrict__ vectors, const __bf16* __restrict__ Wfrag,
    __bf16* __restrict__ buf7)
{
    __shared__ __align__(16) __bf16 Alds[8 * 32 * 40];
    mfma_body<float, __bf16>(vectors + (size_t)21845 * 256, Wfrag,
                             vectors + (size_t)5461 * 256, buf7,
                             (int)blockIdx.x * 32, Alds, 1 << 30);
}

// ---------------------------------------------------------------------------
// K2: L6 (bf16 children -> fp32 out), 128 blocks. One instance.
// ---------------------------------------------------------------------------
__global__ __launch_bounds__(256, 2) void cbt_l6(
    const __bf16* __restrict__ h, const __bf16* __restrict__ Wfrag,
    const float* __restrict__ vec, float* __restrict__ out)
{
    __shared__ __align__(16) __bf16 Alds[8 * 32 * 40];
    mfma_body<__bf16, float>(h, Wfrag, vec, out, (int)blockIdx.x * 32, Alds,
                             1 << 30);
}

// ---------------------------------------------------------------------------
// K3: L5 + L4, 8 blocks, block-local deps, SINGLE mfma_body instance driven
// by a job loop. Block b: jobs 0..3 = L5 tiles 4b..4b+3 (buf6 -> buf5 rows
// 128b..), job 4 = L4 tile b (reads exactly those buf5 rows -> buf4).
// Same-block global RW coherence via __syncthreads (vmcnt drain; proven
// on-silicon in round 10 phase A). Pointer/mBase selection by if-chain
// (SGPR cndmask, no runtime-indexed arrays -> no scratch).
// ---------------------------------------------------------------------------
__global__ __launch_bounds__(256) void cbt_l5l4(
    const float* __restrict__ buf6, const __bf16* __restrict__ Wfrag,
    const float* __restrict__ vectors,
    float* __restrict__ buf5, float* __restrict__ buf4)
{
    __shared__ __align__(16) __bf16 Alds[8 * 32 * 40];
    const int b = (int)blockIdx.x;
#pragma unroll 1
    for (int job = 0; job < 5; ++job) {
        const bool l5 = (job < 4);
        const float* h   = l5 ? buf6 : buf5;
        const float* vec = vectors + (size_t)(l5 ? 341 : 85) * 256;
        float*       out = l5 ? buf5 : buf4;
        const int mBase  = l5 ? (4 * b + job) * 32 : b * 32;
        mfma_body<float, float>(h, Wfrag, vec, out, mBase, Alds, 1 << 30);
        __syncthreads();
    }
}

// ---------------------------------------------------------------------------
// Exact fp32 VALU level over full N=256 (single block): g-combine into LDS
// (G[m][k], stride 516), 16-lane-group dot products over K=512. M <= 4.
// ---------------------------------------------------------------------------
__device__ __forceinline__ void valu_full(
    const float* __restrict__ h, const float* __restrict__ Wl,
    const float* __restrict__ Wr, const float* __restrict__ vec,
    float* __restrict__ out, int M, float* G)
{
    const int tid = threadIdx.x;
    constexpr float C23 = 2.0f / 3.0f, C13 = 1.0f / 3.0f;
    constexpr int GS = 516;

    const int nelem = M * 512;
    for (int e = tid; e < nelem; e += 256) {
        const int m = e >> 9, k = e & 511;
        const float* hm = h + (size_t)m * 1024;
        float g;
        if (k < 256)
            g = hm[k] + C23 * hm[256 + k] + C13 * hm[512 + k];
        else {
            const int kk = k - 256;
            g = C13 * hm[256 + kk] + C23 * hm[512 + kk] + hm[768 + kk];
        }
        G[m * GS + k] = g;
    }
    __syncthreads();

    const int g16 = tid >> 4, l16 = tid & 15;
    const int nout = M * 256;
    for (int o = g16; o < nout; o += 16) {
        const int m = o >> 8;
        const int n = o & 255;
        const float* wlp = Wl + (size_t)n * 256;
        const float* wrp = Wr + (size_t)n * 256;
        float acc = 0.0f;
#pragma unroll
        for (int q = 0; q < 8; ++q) {
            const int k = l16 * 4 + q * 64;
            const float4 gv = *reinterpret_cast<const float4*>(&G[m * GS + k]);
            const float4 wv = (q < 4)
                ? *reinterpret_cast<const float4*>(wlp + k)
                : *reinterpret_cast<const float4*>(wrp + (k - 256));
            acc += gv.x * wv.x + gv.y * wv.y + gv.z * wv.z + gv.w * wv.w;
        }
#pragma unroll
        for (int off = 8; off >= 1; off >>= 1)
            acc += __shfl_xor(acc, off, 64);
        if (l16 == 0) {
            const size_t idx = (size_t)m * 256 + n;
            out[idx] = fast_tanh(acc + vec[idx]);
        }
    }
    __syncthreads();
}

// ---------------------------------------------------------------------------
// K4: L3..L0 in ONE block. Job loop: 3 MFMA tiles (L3 t0, L3 t1, L2 guarded)
// through ONE mfma_body instance, then 2 valu levels through ONE valu_full
// instance. Cross-block dep on buf4 crosses the kernel boundary.
// ---------------------------------------------------------------------------
__global__ __launch_bounds__(256) void cbt_tail1(
    const float* __restrict__ buf4, const __bf16* __restrict__ Wfrag,
    const float* __restrict__ Wl, const float* __restrict__ Wr,
    const float* __restrict__ vectors,
    float* __restrict__ buf3, float* __restrict__ buf2,
    float* __restrict__ buf1, float* __restrict__ outF)
{
    __shared__ __align__(16) __bf16 Alds[8 * 32 * 40];   // 20 KB
    __shared__ __align__(16) float shG[4 * 516];         // 8.3 KB (M<=4 valu)

#pragma unroll 1
    for (int job = 0; job < 3; ++job) {
        const bool l3 = (job < 2);
        const float* h   = l3 ? buf4 : buf3;
        const float* vec = vectors + (size_t)(l3 ? 21 : 5) * 256;
        float*       out = l3 ? buf3 : buf2;
        const int mBase  = (job == 1) ? 32 : 0;
        const int lim    = l3 ? (1 << 30) : 16;
        mfma_body<float, float>(h, Wfrag, vec, out, mBase, Alds, lim);
        __syncthreads();
    }
#pragma unroll 1
    for (int job = 0; job < 2; ++job) {
        const bool l1 = (job == 0);
        const float* h   = l1 ? buf2 : buf1;
        const float* vec = l1 ? vectors + (size_t)1 * 256 : vectors;
        float*       out = l1 ? buf1 : outF;
        valu_full(h, Wl, Wr, vec, out, l1 ? 4 : 1, shG);
    }
}

// ---------------------------------------------------------------------------
extern "C" void kernel_launch(void* const* d_in, const int* in_sizes, int n_in,
                              void* d_out, int out_size, void* d_ws, size_t ws_size,
                              hipStream_t stream) {
    const float* vectors = (const float*)d_in[0];
    const float* Wl = (const float*)d_in[1];
    const float* Wr = (const float*)d_in[2];
    float* outF = (float*)d_out;

    // ws layout:
    //   buf7  bf16  16384x256 (8 MB)   L7 out
    //   buf6  f32    4096x256 (4 MB)   L6 out
    //   buf5  f32    1024x256 (1 MB)   L5 out
    //   buf4  f32     256x256 (256 KB) L4 out
    //   buf3  f32      64x256 (64 KB)  L3 out
    //   buf2  f32      16x256 (16 KB)  L2 out
    //   buf1  f32       4x256 (4 KB)   L1 out
    //   Wfrag bf16  16384x8   (256 KB)
    char* p = (char*)d_ws;
    __bf16* buf7 = (__bf16*)p;           p += (size_t)16384 * 256 * 2;
    float*  buf6 = (float*)p;            p += (size_t)4096 * 256 * 4;
    float*  buf5 = (float*)p;            p += (size_t)1024 * 256 * 4;
    float*  buf4 = (float*)p;            p += (size_t)256 * 256 * 4;
    float*  buf3 = (float*)p;            p += (size_t)64 * 256 * 4;
    float*  buf2 = (float*)p;            p += (size_t)16 * 256 * 4;
    float*  buf1 = (float*)p;            p += (size_t)4 * 256 * 4;
    __bf16* Wfrag = (__bf16*)p;

    // K0: weight swizzle
    hipLaunchKernelGGL(cbt_wconv, dim3(64), dim3(256), 0, stream, Wl, Wr, Wfrag);
    // K1: L7 (512 tile-blocks)
    hipLaunchKernelGGL(cbt_l7, dim3(512), dim3(256), 0, stream,
                       vectors, Wfrag, buf7);
    // K2: L6
    hipLaunchKernelGGL(cbt_l6, dim3(128), dim3(256), 0, stream,
                       buf7, Wfrag, vectors + (size_t)1365 * 256, buf6);
    // K3: L5+L4 (8 blocks, block-local deps, single mfma instance)
    hipLaunchKernelGGL(cbt_l5l4, dim3(8), dim3(256), 0, stream,
                       buf6, Wfrag, vectors, buf5, buf4);
    // K4: L3..L0 (1 block, single mfma instance + single valu instance)
    hipLaunchKernelGGL(cbt_tail1, dim3(1), dim3(256), 0, stream,
                       buf4, Wfrag, Wl, Wr, vectors, buf3, buf2, buf1, outF);
}